// Round 3
// baseline (741.762 us; speedup 1.0000x reference)
//
#include <hip/hip_runtime.h>

#define IN_K   4096
#define OUT_N  4096
#define M_ROWS 8192
#define RANK   32

typedef short bf16x8 __attribute__((ext_vector_type(8)));      // 8 bf16 in 4 VGPRs
typedef float f32x4  __attribute__((ext_vector_type(4)));
typedef unsigned short u16;
typedef unsigned short us4 __attribute__((ext_vector_type(4)));
typedef __attribute__((address_space(1))) const void* gptr_t;
typedef __attribute__((address_space(3))) void* lptr_t;

static __device__ __forceinline__ u16 f2bf(float f) {
  // round-to-nearest-even bf16 truncation (inputs are finite normals)
  unsigned int x = __float_as_uint(f);
  unsigned int r = (x + 0x7fffu + ((x >> 16) & 1u)) >> 16;
  return (u16)r;
}

// ---------- W fp32 = codebook[indices] + (U*s) @ Vt ----------
// grid: (OUT/16, IN/1024), block 256
__global__ __launch_bounds__(256) void dequant_kernel(
    const float* __restrict__ codebook, const int* __restrict__ indices,
    const float* __restrict__ U, const float* __restrict__ s,
    const float* __restrict__ Vt, float* __restrict__ Wf) {
  __shared__ float Us[16][RANK];
  __shared__ float Vs[RANK][256];
  const int o0 = blockIdx.x * 16;
  const int i0 = blockIdx.y * 1024;
  const int tid = threadIdx.x;
  for (int e = tid; e < 16 * RANK; e += 256) {
    int o = e >> 5, r = e & 31;
    Us[o][r] = U[(o0 + o) * RANK + r] * s[r];
  }
  for (int chunk = 0; chunk < 4; ++chunk) {
    const int ib = i0 + chunk * 256;
    __syncthreads();
    for (int e = tid; e < RANK * 256; e += 256) {
      int r = e >> 8, ii = e & 255;
      Vs[r][ii] = Vt[r * IN_K + ib + ii];
    }
    __syncthreads();
    const int i = ib + tid;
    #pragma unroll 4
    for (int o = 0; o < 16; ++o) {
      float acc = codebook[indices[(size_t)(o0 + o) * IN_K + i]];
      #pragma unroll
      for (int r = 0; r < RANK; ++r) acc += Us[o][r] * Vs[r][tid];
      Wf[(size_t)(o0 + o) * IN_K + i] = acc;
    }
  }
}

// ---------- sparse sidecar scatter-add ----------
__global__ __launch_bounds__(256) void scatter_kernel(
    const int* __restrict__ rows, const int* __restrict__ cols,
    const float* __restrict__ deltas, float* __restrict__ Wf, int nnz) {
  int e = blockIdx.x * 256 + threadIdx.x;
  if (e < nnz) atomicAdd(&Wf[(size_t)rows[e] * IN_K + cols[e]], deltas[e]);
}

// ---------- fp32 -> bf16 convert, 4 elems/thread ----------
__global__ __launch_bounds__(256) void convert_kernel(
    const float* __restrict__ src, u16* __restrict__ dst, int n4) {
  int i = blockIdx.x * 256 + threadIdx.x;
  const int stride = gridDim.x * 256;
  for (; i < n4; i += stride) {
    float4 v = ((const float4*)src)[i];
    us4 o = { f2bf(v.x), f2bf(v.y), f2bf(v.z), f2bf(v.w) };
    *(us4*)(dst + (size_t)i * 4) = o;
  }
}

// ---------- bf16 GEMM: out[m][n] = sum_k Xb[m][k]*Wb[n][k] + bias[n] ----------
// 128x128 tile, BK=64, 4 waves (2x2), each wave 64x64 = 4x4 MFMA 16x16x32 frags
__global__ __launch_bounds__(256) void gemm_kernel(
    const u16* __restrict__ Xb, const u16* __restrict__ Wb,
    const float* __restrict__ bias, float* __restrict__ out) {
  __shared__ u16 Al[128 * 64];   // 16 KiB
  __shared__ u16 Bl[128 * 64];   // 16 KiB
  const int tid  = threadIdx.x;
  const int lane = tid & 63;
  const int w    = tid >> 6;
  const int brow = blockIdx.y * 128;   // M tile
  const int bcol = blockIdx.x * 128;   // N tile (W rows)
  const int m_w  = (w >> 1) * 64;
  const int n_w  = (w & 1) * 64;

  f32x4 acc[4][4];
  #pragma unroll
  for (int a = 0; a < 4; ++a)
    #pragma unroll
    for (int b = 0; b < 4; ++b) acc[a][b] = (f32x4){0.f, 0.f, 0.f, 0.f};

  const int srow = lane >> 3;          // 0..7 row within 8-row chunk
  const int sko  = (lane & 7) * 8;     // k element offset (16B granules)

  for (int kt = 0; kt < IN_K; kt += 64) {
    // stage A and B tiles: 16 chunks of 1 KiB each per tile, 4 chunks/wave
    #pragma unroll
    for (int t = 0; t < 4; ++t) {
      const int c = w * 4 + t;               // wave-uniform
      const int row = c * 8 + srow;
      __builtin_amdgcn_global_load_lds(
          (gptr_t)(Xb + (size_t)(brow + row) * IN_K + kt + sko),
          (lptr_t)(Al + c * 512), 16, 0, 0);
      __builtin_amdgcn_global_load_lds(
          (gptr_t)(Wb + (size_t)(bcol + row) * IN_K + kt + sko),
          (lptr_t)(Bl + c * 512), 16, 0, 0);
    }
    __syncthreads();   // drains vmcnt before barrier release

    #pragma unroll
    for (int kk = 0; kk < 2; ++kk) {
      bf16x8 af[4], bfr[4];
      #pragma unroll
      for (int mi = 0; mi < 4; ++mi)
        af[mi] = *(const bf16x8*)&Al[(m_w + mi * 16 + (lane & 15)) * 64 + kk * 32 + (lane >> 4) * 8];
      #pragma unroll
      for (int ni = 0; ni < 4; ++ni)
        bfr[ni] = *(const bf16x8*)&Bl[(n_w + ni * 16 + (lane & 15)) * 64 + kk * 32 + (lane >> 4) * 8];
      #pragma unroll
      for (int mi = 0; mi < 4; ++mi)
        #pragma unroll
        for (int ni = 0; ni < 4; ++ni)
          acc[mi][ni] = __builtin_amdgcn_mfma_f32_16x16x32_bf16(af[mi], bfr[ni], acc[mi][ni], 0, 0, 0);
    }
    __syncthreads();
  }

  // epilogue: C/D layout col=lane&15, row=(lane>>4)*4+j
  const int r0 = (lane >> 4) * 4;
  const int c0 = lane & 15;
  float bv[4];
  #pragma unroll
  for (int ni = 0; ni < 4; ++ni) bv[ni] = bias[bcol + n_w + ni * 16 + c0];
  #pragma unroll
  for (int mi = 0; mi < 4; ++mi)
    #pragma unroll
    for (int ni = 0; ni < 4; ++ni) {
      float* op = out + (size_t)(brow + m_w + mi * 16 + r0) * OUT_N + (bcol + n_w + ni * 16 + c0);
      #pragma unroll
      for (int j = 0; j < 4; ++j)
        op[(size_t)j * OUT_N] = acc[mi][ni][j] + bv[ni];
    }
}

extern "C" void kernel_launch(void* const* d_in, const int* in_sizes, int n_in,
                              void* d_out, int out_size, void* d_ws, size_t ws_size,
                              hipStream_t stream) {
  const float* x        = (const float*)d_in[0];
  const float* codebook = (const float*)d_in[1];
  const int*   indices  = (const int*)d_in[2];
  const int*   srows    = (const int*)d_in[3];
  const int*   scols    = (const int*)d_in[4];
  const float* sdeltas  = (const float*)d_in[5];
  const float* U        = (const float*)d_in[6];
  const float* s        = (const float*)d_in[7];
  const float* Vt       = (const float*)d_in[8];
  const float* bias     = (const float*)d_in[9];
  float* out = (float*)d_out;

  char* ws = (char*)d_ws;
  float* Wf = (float*)ws;                                  // 64 MiB fp32 W
  u16*   Wb = (u16*)(ws + (size_t)(64u << 20));            // 32 MiB bf16 W
  u16*   Xb = (u16*)(ws + (size_t)(96u << 20));            // 64 MiB bf16 x

  const int nnz = in_sizes[3];

  dequant_kernel<<<dim3(OUT_N / 16, IN_K / 1024), 256, 0, stream>>>(
      codebook, indices, U, s, Vt, Wf);
  scatter_kernel<<<(nnz + 255) / 256, 256, 0, stream>>>(srows, scols, sdeltas, Wf, nnz);
  convert_kernel<<<2048, 256, 0, stream>>>(Wf, Wb, OUT_N * IN_K / 4);
  convert_kernel<<<2048, 256, 0, stream>>>(x, Xb, M_ROWS * IN_K / 4);
  gemm_kernel<<<dim3(OUT_N / 128, M_ROWS / 128), 256, 0, stream>>>(Xb, Wb, bias, out);
}

// Round 7
// 700.148 us; speedup vs baseline: 1.0594x; 1.0594x over previous
//
#include <hip/hip_runtime.h>

#define IN_K   4096
#define OUT_N  4096
#define M_ROWS 8192
#define RANK   32

typedef short bf16x8 __attribute__((ext_vector_type(8)));
typedef float f32x4  __attribute__((ext_vector_type(4)));
typedef unsigned short u16;
typedef unsigned short us4 __attribute__((ext_vector_type(4)));
typedef __attribute__((address_space(1))) const void* gptr_t;
typedef __attribute__((address_space(3))) void* lptr_t;

static __device__ __forceinline__ u16 f2bf(float f) {
  unsigned int x = __float_as_uint(f);
  unsigned int r = (x + 0x7fffu + ((x >> 16) & 1u)) >> 16;
  return (u16)r;
}

// ---------- W fp32 = codebook[indices] + (U*s) @ Vt ----------
// block: 16 rows x 256 cols. grid (IN/256, OUT/16).
__global__ __launch_bounds__(256) void dequant_kernel(
    const float* __restrict__ cb, const int* __restrict__ idx,
    const float* __restrict__ U, const float* __restrict__ s,
    const float* __restrict__ Vt, float* __restrict__ Wf) {
  __shared__ float us[16][RANK];
  const int o0 = blockIdx.y * 16;
  const int i  = blockIdx.x * 256 + threadIdx.x;
  for (int e = threadIdx.x; e < 16 * RANK; e += 256) {
    int oo = e >> 5, r = e & 31;
    us[oo][r] = U[(o0 + oo) * RANK + r] * s[r];
  }
  __syncthreads();
  float acc[16];
  #pragma unroll
  for (int oo = 0; oo < 16; ++oo)
    acc[oo] = cb[idx[(size_t)(o0 + oo) * IN_K + i]];
  #pragma unroll 8
  for (int r = 0; r < RANK; ++r) {
    float v = Vt[r * IN_K + i];
    #pragma unroll
    for (int oo = 0; oo < 16; ++oo) acc[oo] += us[oo][r] * v;
  }
  #pragma unroll
  for (int oo = 0; oo < 16; ++oo)
    Wf[(size_t)(o0 + oo) * IN_K + i] = acc[oo];
}

// ---------- sparse sidecar scatter-add ----------
__global__ __launch_bounds__(256) void scatter_kernel(
    const int* __restrict__ rows, const int* __restrict__ cols,
    const float* __restrict__ deltas, float* __restrict__ Wf, int nnz) {
  int e = blockIdx.x * 256 + threadIdx.x;
  if (e < nnz) atomicAdd(&Wf[(size_t)rows[e] * IN_K + cols[e]], deltas[e]);
}

// ---------- fused fp32->bf16 convert of two buffers ----------
__global__ __launch_bounds__(256) void convert2_kernel(
    const float* __restrict__ a, u16* __restrict__ da, int na4,
    const float* __restrict__ b, u16* __restrict__ db, int nb4) {
  int i = blockIdx.x * 256 + threadIdx.x;
  const int stride = gridDim.x * 256;
  const int tot = na4 + nb4;
  for (; i < tot; i += stride) {
    const float4* src; u16* dst; int j;
    if (i < na4) { src = (const float4*)a; dst = da; j = i; }
    else         { src = (const float4*)b; dst = db; j = i - na4; }
    float4 v = src[j];
    us4 o = { f2bf(v.x), f2bf(v.y), f2bf(v.z), f2bf(v.w) };
    *(us4*)(dst + (size_t)j * 4) = o;
  }
}

// ---------- 256x256 8-phase bf16 GEMM ----------
// out[m][n] = sum_k Xb[m][k]*Wb[n][k] + bias[n]
// 8 waves (wm 0..1, wn 0..3); wave owns 128x64 output.
// LDS: A/B tiles [2 dbuf][256 rows][64 cols] bf16, XOR-swizzled in 16B granules.
__global__ __launch_bounds__(512, 2) void gemm_kernel(
    const u16* __restrict__ Xb, const u16* __restrict__ Wb,
    const float* __restrict__ bias, float* __restrict__ out) {
  __shared__ u16 Atile[2][16384];   // 64 KiB
  __shared__ u16 Btile[2][16384];   // 64 KiB
  const int tid  = threadIdx.x;
  const int lane = tid & 63;
  const int w    = tid >> 6;
  const int wm   = w >> 2;          // 0..1
  const int wn   = w & 3;           // 0..3
  const int fr   = lane & 15;
  const int fq   = lane >> 4;       // 0..3

  // XCD-aware bijective swizzle of 512 workgroups (512 % 8 == 0)
  const int bid0 = blockIdx.y * gridDim.x + blockIdx.x;
  const int bid  = (bid0 & 7) * 64 + (bid0 >> 3);
  const int bx   = bid & 15;        // N-block
  const int by   = bid >> 4;        // M-block
  const int brow = by * 256;
  const int bcol = bx * 256;

  // staging lane constants: row-sub = lane>>3, source granule = (lane&7)^(lane>>3)
  const int srow = lane >> 3;
  const int sgr  = ((lane & 7) ^ srow) * 8;   // element offset in source row

  f32x4 acc[8][4];
  #pragma unroll
  for (int a = 0; a < 8; ++a)
    #pragma unroll
    for (int b = 0; b < 4; ++b) acc[a][b] = (f32x4){0.f, 0.f, 0.f, 0.f};

  // stage half-tile p (0:A rows0-127, 1:A rows128-255, 2:B 0-127, 3:B 128-255)
  // of K-column kcol into buffer nb. 2 x global_load_lds(16B) per thread.
  #define STAGE_HALF(nb, kcol, p)                                              \
    {                                                                          \
      u16* tile = ((p) < 2) ? Atile[nb] : Btile[nb];                           \
      const u16* gsrc = ((p) < 2) ? Xb : Wb;                                   \
      const int gbase = ((p) < 2) ? brow : bcol;                               \
      _Pragma("unroll")                                                        \
      for (int q = 0; q < 2; ++q) {                                            \
        const int lr = ((p) & 1) * 128 + q * 64 + w * 8;  /* wave-uniform */   \
        __builtin_amdgcn_global_load_lds(                                      \
            (gptr_t)(gsrc + (size_t)(gbase + lr + srow) * IN_K + (kcol) + sgr),\
            (lptr_t)(tile + lr * 64), 16, 0, 0);                               \
      }                                                                        \
    }

  // prologue: stage K-tile 0 into buf 0
  #pragma unroll
  for (int p = 0; p < 4; ++p) STAGE_HALF(0, 0, p)
  asm volatile("s_waitcnt vmcnt(0)" ::: "memory");
  __builtin_amdgcn_s_barrier();

  bf16x8 bq[4];   // B fragments, persist across the two phases sharing kk

  for (int t = 0; t < 64; ++t) {
    const int cur = t & 1;
    const int kn  = (t + 1) * 64;
    const bool pf = (t < 63);
    const u16* Ac = Atile[cur];
    const u16* Bc = Btile[cur];

    #pragma unroll
    for (int p = 0; p < 4; ++p) {
      const int mh = p & 1;         // M-half of this wave's 128 rows
      const int kk = p >> 1;        // K-subtile (32 elems)
      // issue next K-tile's half-tile p (lands in the other buffer)
      if (pf) STAGE_HALF(cur ^ 1, kn, p)

      // swizzled read granule: row&7 == lane&7 for all frag rows
      const int g0 = (((kk * 4) + fq) ^ (lane & 7)) * 8;
      if ((p & 1) == 0) {           // load B frags for this kk (reused next phase)
        #pragma unroll
        for (int ni = 0; ni < 4; ++ni)
          bq[ni] = *(const bf16x8*)&Bc[(wn * 64 + ni * 16 + fr) * 64 + g0];
      }
      bf16x8 af[4];
      #pragma unroll
      for (int mi = 0; mi < 4; ++mi)
        af[mi] = *(const bf16x8*)&Ac[(wm * 128 + mh * 64 + mi * 16 + fr) * 64 + g0];

      __builtin_amdgcn_s_barrier();          // phase alignment (no counter drain)
      __builtin_amdgcn_s_setprio(1);
      #pragma unroll
      for (int mi = 0; mi < 4; ++mi)
        #pragma unroll
        for (int ni = 0; ni < 4; ++ni)
          acc[mh * 4 + mi][ni] =
              __builtin_amdgcn_mfma_f32_16x16x32_bf16(af[mi], bq[ni],
                                                      acc[mh * 4 + mi][ni], 0, 0, 0);
      __builtin_amdgcn_s_setprio(0);
      if (p == 3) {
        // wait only this K-tile's 8 prefetch loads (issued over the last 4
        // phases -> mostly landed), then release the buffer swap.
        asm volatile("s_waitcnt vmcnt(0)" ::: "memory");
      }
      __builtin_amdgcn_s_barrier();
      if (p == 3) __builtin_amdgcn_sched_barrier(0);
    }
  }
  #undef STAGE_HALF

  // epilogue: C/D layout col = lane&15, row = fq*4 + j
  float bv[4];
  #pragma unroll
  for (int ni = 0; ni < 4; ++ni) bv[ni] = bias[bcol + wn * 64 + ni * 16 + fr];
  #pragma unroll
  for (int am = 0; am < 8; ++am)
    #pragma unroll
    for (int ni = 0; ni < 4; ++ni) {
      float* op = out + (size_t)(brow + wm * 128 + am * 16 + fq * 4) * OUT_N
                      + (bcol + wn * 64 + ni * 16 + fr);
      #pragma unroll
      for (int j = 0; j < 4; ++j)
        op[(size_t)j * OUT_N] = acc[am][ni][j] + bv[ni];
    }
}

extern "C" void kernel_launch(void* const* d_in, const int* in_sizes, int n_in,
                              void* d_out, int out_size, void* d_ws, size_t ws_size,
                              hipStream_t stream) {
  const float* x        = (const float*)d_in[0];
  const float* codebook = (const float*)d_in[1];
  const int*   indices  = (const int*)d_in[2];
  const int*   srows    = (const int*)d_in[3];
  const int*   scols    = (const int*)d_in[4];
  const float* sdeltas  = (const float*)d_in[5];
  const float* U        = (const float*)d_in[6];
  const float* s        = (const float*)d_in[7];
  const float* Vt       = (const float*)d_in[8];
  const float* bias     = (const float*)d_in[9];
  float* out = (float*)d_out;

  char* ws = (char*)d_ws;
  float* Wf = (float*)ws;                                  // 64 MiB fp32 W
  u16*   Wb = (u16*)(ws + (size_t)(64u << 20));            // 32 MiB bf16 W
  u16*   Xb = (u16*)(ws + (size_t)(96u << 20));            // 64 MiB bf16 x

  const int nnz = in_sizes[3];

  dequant_kernel<<<dim3(IN_K / 256, OUT_N / 16), 256, 0, stream>>>(
      codebook, indices, U, s, Vt, Wf);
  scatter_kernel<<<(nnz + 255) / 256, 256, 0, stream>>>(srows, scols, sdeltas, Wf, nnz);
  convert2_kernel<<<4096, 256, 0, stream>>>(
      Wf, Wb, OUT_N * IN_K / 4, x, Xb, M_ROWS * IN_K / 4);
  gemm_kernel<<<dim3(OUT_N / 256, M_ROWS / 256), 512, 0, stream>>>(Xb, Wb, bias, out);
}